// Round 17
// baseline (76.749 us; speedup 1.0000x reference)
//
#include <hip/hip_runtime.h>

// ConvCapsuleLayer r17: X pre-converted to padded fp16 im2col layout (xprep) ->
// conv A-fragments load DIRECTLY from global with pure-offset addressing.
// No X staging, no bounds checks (padded dims), LDS = votesT only (18432 B).
// Transpose + DPP routing byte-identical to r16. 2048 blocks x 256 thr.

typedef __attribute__((ext_vector_type(2))) _Float16 f16x2;
typedef __attribute__((ext_vector_type(8))) _Float16 f16x8;
typedef __attribute__((ext_vector_type(16))) float f32x16;

union f16x8u { f16x8 v; f16x2 d[4]; unsigned short s[8]; unsigned int u32[4]; unsigned long long u[2]; };
union f16x2u { f16x2 v; unsigned int u; unsigned short s[2]; };

__device__ __forceinline__ unsigned short f2h(float x) {
  union { _Float16 h; unsigned short u; } v;
  v.h = (_Float16)x;
  return v.u;
}

template<int CTRL>
__device__ __forceinline__ float dpp_mov(float x) {
  return __builtin_bit_cast(float, __builtin_amdgcn_update_dpp(
      0, __builtin_bit_cast(int, x), CTRL, 0xF, 0xF, true));
}
// sum over 8-lane c-group: ^1, ^2, ^7(mirror) — order-free for sums
__device__ __forceinline__ float sum8_dpp(float x) {
  x += dpp_mov<0xB1>(x);    // quad_perm [1,0,3,2]  : ^1
  x += dpp_mov<0x4E>(x);    // quad_perm [2,3,0,1]  : ^2
  x += dpp_mov<0x141>(x);   // row_half_mirror      : ^7
  return x;
}

// W[5][5][16][256] f32 -> wsh fp16 [khkw 25][ch 256][ia 16]
__global__ __launch_bounds__(256) void wprep_kernel(
    const float* __restrict__ W, unsigned short* __restrict__ wsh) {
  int t = blockIdx.x * 256 + threadIdx.x;      // 102400 total
  int khkw = t >> 12;
  int rem  = t & 4095;
  int ch = rem >> 4, ia = rem & 15;
  wsh[t] = f2h(W[khkw * 4096 + ia * 256 + ch]);
}

// inp f32 [16][32][32][8][16] -> xt fp16 [n 128][hp 36][wp 36][ia 16], zero borders.
// n = bb*8+ii (votes-image order): b_src=(bb&1)*8+ii, i_src=bb>>1 (r1-verified scramble).
__global__ __launch_bounds__(256) void xprep_kernel(
    const float* __restrict__ inp, _Float16* __restrict__ xt) {
  int idx = blockIdx.x * 256 + threadIdx.x;    // 663552 = 2592 * 256
  int pos = idx >> 2, iaq = idx & 3;
  int n  = pos / 1296;
  int r  = pos - n * 1296;
  int hp = r / 36;
  int wp = r - hp * 36;
  int bb = n >> 3, ii = n & 7;
  int b_src = (bb & 1) * 8 + ii, i_src = bb >> 1;
  int hh = hp - 2, ww = wp - 2;
  unsigned long long u = 0ull;
  if ((unsigned)hh < 32u && (unsigned)ww < 32u) {
    float4 v = *(const float4*)(inp +
        ((((size_t)b_src * 32 + hh) * 32 + ww) * 8 + i_src) * 16 + iaq * 4);
    union { _Float16 hx[4]; unsigned long long uu; } pk;
    pk.hx[0] = (_Float16)v.x; pk.hx[1] = (_Float16)v.y;
    pk.hx[2] = (_Float16)v.z; pk.hx[3] = (_Float16)v.w;
    u = pk.uu;
  }
  *(unsigned long long*)(xt + (size_t)pos * 16 + iaq * 4) = u;
}

// LDS map (18432 B): votesT fp16 [wslot 4, stride 4608][grp 64, stride 72][j 4][ii 8]
// (two passes: wslot=w for w0-3 (mt=0), then w-4 for w4-7 (mt=1))
__global__ __launch_bounds__(256, 4) void capsconv_mfma_kernel(
    const _Float16* __restrict__ xt,          // [128][36][36][16] fp16, padded
    const unsigned short* __restrict__ wsh,   // [25][256][16] fp16
    const float* __restrict__ bias,           // [256] f32
    float* __restrict__ out)                  // [16][32][32][256] f32
{
  __shared__ char smem[18432];
  const _Float16* wshh = (const _Float16*)wsh;

  const int tid  = threadIdx.x;
  const int wid  = tid >> 6;          // wave 0..3: conv ch quarter; routing w slot
  const int lane = tid & 63;
  const int sub  = lane >> 5;
  const int ln31 = lane & 31;

  const int bid = blockIdx.x;         // 2048 = ((bb*32 + h)*4 + wq)
  const int wq = bid & 3;
  const int h  = (bid >> 2) & 31;
  const int bb = bid >> 7;

  // ---------------- conv: A direct from padded global xt, 25 taps ----------------
  // lane ln31 -> image n = bb*8 + (ln31&7), padded row h+kh, padded col wq*8+(ln31>>3)+kw
  f32x16 acc[2][2];
  #pragma unroll
  for (int mt = 0; mt < 2; ++mt)
    #pragma unroll
    for (int nt = 0; nt < 2; ++nt)
      #pragma unroll
      for (int e = 0; e < 16; ++e) acc[mt][nt][e] = 0.f;

  const _Float16* aBase = xt +
      (((size_t)(bb * 8 + (ln31 & 7)) * 36 + h) * 36 + wq * 8 + (ln31 >> 3)) * 16 + sub * 8;
  const _Float16* bBase = wshh + (wid * 64 + ln31) * 16 + sub * 8;

  #pragma unroll
  for (int kh = 0; kh < 5; ++kh) {
    const _Float16* aK = aBase + kh * 576;     // 36*16 elems per padded row
    #pragma unroll
    for (int kw = 0; kw < 5; ++kw) {
      f16x8 af0 = *(const f16x8*)(aK + kw * 16);          // rows mt=0 (w 0-3)
      f16x8 af1 = *(const f16x8*)(aK + (kw + 4) * 16);    // rows mt=1 (w 4-7)
      f16x8 bf0 = *(const f16x8*)(bBase + (size_t)(kh * 5 + kw) * 4096);
      f16x8 bf1 = *(const f16x8*)(bBase + (size_t)(kh * 5 + kw) * 4096 + 512);
      acc[0][0] = __builtin_amdgcn_mfma_f32_32x32x16_f16(af0, bf0, acc[0][0], 0, 0, 0);
      acc[0][1] = __builtin_amdgcn_mfma_f32_32x32x16_f16(af0, bf1, acc[0][1], 0, 0, 0);
      acc[1][0] = __builtin_amdgcn_mfma_f32_32x32x16_f16(af1, bf0, acc[1][0], 0, 0, 0);
      acc[1][1] = __builtin_amdgcn_mfma_f32_32x32x16_f16(af1, bf1, acc[1][1], 0, 0, 0);
    }
  }

  // ---------------- two-phase transpose + register pickup (3 barriers) ----------------
  // acc[mt][nt][q*4+t] = vote(w=mt*4+q, ii=t+4sub, ch=wid*64+nt*32+ln31)
  float vv[2][4][8];   // [p=mt][j][ii], w = mt*4 + wid
  {
    const int ch0 = wid * 64 + ln31;
    char* base0 = smem + (ch0 >> 2) * 72 + (ch0 & 3) * 16 + sub * 8;
    const int ch1 = ch0 + 32;
    char* base1 = smem + (ch1 >> 2) * 72 + (ch1 & 3) * 16 + sub * 8;
    #pragma unroll
    for (int mt = 0; mt < 2; ++mt) {
      if (mt) __syncthreads();   // pass-A reads complete before overwrite
      #pragma unroll
      for (int q = 0; q < 4; ++q) {
        f16x2u lo0, hi0, lo1, hi1;
        lo0.v = f16x2{(_Float16)acc[mt][0][q * 4 + 0], (_Float16)acc[mt][0][q * 4 + 1]};
        hi0.v = f16x2{(_Float16)acc[mt][0][q * 4 + 2], (_Float16)acc[mt][0][q * 4 + 3]};
        lo1.v = f16x2{(_Float16)acc[mt][1][q * 4 + 0], (_Float16)acc[mt][1][q * 4 + 1]};
        hi1.v = f16x2{(_Float16)acc[mt][1][q * 4 + 2], (_Float16)acc[mt][1][q * 4 + 3]};
        *(unsigned long long*)(base0 + q * 4608) =
            (unsigned long long)lo0.u | ((unsigned long long)hi0.u << 32);
        *(unsigned long long*)(base1 + q * 4608) =
            (unsigned long long)lo1.u | ((unsigned long long)hi1.u << 32);
      }
      __syncthreads();
      #pragma unroll
      for (int j = 0; j < 4; ++j) {
        f16x8u t8;
        t8.v = *(const f16x8*)(smem + wid * 4608 + lane * 72 + j * 16);
        #pragma unroll
        for (int ii = 0; ii < 8; ++ii) vv[mt][j][ii] = (float)t8.v[ii];
      }
    }
  }

  // ---------------- routing: wave wid owns w = wid + 4p; DPP reductions ----------------
  const int k = lane & 7;             // c-group slot; c = lane>>3
  const float4 bv4 = *(const float4*)(bias + lane * 4);
  const float bvj[4] = {bv4.x, bv4.y, bv4.z, bv4.w};

  float logit_k[2] = {0.f, 0.f};
  float pre[2][4], scale[2] = {0.f, 0.f};

  #pragma unroll
  for (int rt = 0; rt < 3; ++rt) {
    #pragma unroll
    for (int p = 0; p < 2; ++p) {
      float r[8];
      if (rt == 0) {
        #pragma unroll
        for (int i = 0; i < 8; ++i) r[i] = 0.125f;
      } else {
        // softmax over c: lanes stride 8 -> ^8 via DPP ror8, ^16/^32 via shfl
        float mx = logit_k[p];
        mx = fmaxf(mx, dpp_mov<0x128>(mx));             // row_ror:8 = ^8
        mx = fmaxf(mx, __shfl_xor(mx, 16, 64));
        mx = fmaxf(mx, __shfl_xor(mx, 32, 64));
        float e = __expf(logit_k[p] - mx);
        float den = e;
        den += dpp_mov<0x128>(den);
        den += __shfl_xor(den, 16, 64);
        den += __shfl_xor(den, 32, 64);
        float route_k = e / den;
        int cbase = lane & 56;          // c<<3
        #pragma unroll
        for (int i = 0; i < 8; ++i) r[i] = __shfl(route_k, cbase | i, 64);
      }
      #pragma unroll
      for (int j = 0; j < 4; ++j) {
        float pp = bvj[j];
        #pragma unroll
        for (int ii = 0; ii < 8; ++ii) pp = fmaf(r[ii], vv[p][j][ii], pp);
        pre[p][j] = pp;
      }
      // squash scale: nsq over 32 atoms = 8-lane c-group DPP reduce
      float nsq = pre[p][0] * pre[p][0] + pre[p][1] * pre[p][1] +
                  pre[p][2] * pre[p][2] + pre[p][3] * pre[p][3];
      nsq = sum8_dpp(nsq);
      scale[p] = sqrtf(nsq) / (1.f + nsq);
      if (rt < 2) {
        // agreement: dot8[ii] over 32 atoms via DPP trees (0 DS ops)
        float dot8[8];
        #pragma unroll
        for (int ii = 0; ii < 8; ++ii) {
          float d = vv[p][0][ii] * pre[p][0];
          d = fmaf(vv[p][1][ii], pre[p][1], d);
          d = fmaf(vv[p][2][ii], pre[p][2], d);
          d = fmaf(vv[p][3][ii], pre[p][3], d);
          dot8[ii] = sum8_dpp(d);
        }
        bool b0 = (k & 1), b1 = (k & 2), b2 = (k & 4);
        float e0 = b0 ? dot8[1] : dot8[0];
        float e1 = b0 ? dot8[3] : dot8[2];
        float e2 = b0 ? dot8[5] : dot8[4];
        float e3 = b0 ? dot8[7] : dot8[6];
        float f0 = b1 ? e1 : e0;
        float f1 = b1 ? e3 : e2;
        logit_k[p] = fmaf(scale[p], b2 ? f1 : f0, logit_k[p]);
      }
    }
  }
  // final act = pre * scale; coalesced float4 per position (w = wid + 4p)
  const size_t base8 = (size_t)((bb * 32 + h) * 32 + wq * 8);
  #pragma unroll
  for (int p = 0; p < 2; ++p) {
    float4 o = make_float4(pre[p][0] * scale[p], pre[p][1] * scale[p],
                           pre[p][2] * scale[p], pre[p][3] * scale[p]);
    *(float4*)(out + (base8 + wid + 4 * p) * 256 + lane * 4) = o;
  }
}

extern "C" void kernel_launch(void* const* d_in, const int* in_sizes, int n_in,
                              void* d_out, int out_size, void* d_ws, size_t ws_size,
                              hipStream_t stream) {
  (void)in_sizes; (void)n_in; (void)ws_size; (void)out_size;
  const float* inp  = (const float*)d_in[0];
  const float* W    = (const float*)d_in[1];
  const float* bv   = (const float*)d_in[2];
  float* out        = (float*)d_out;
  unsigned short* wsh = (unsigned short*)d_ws;                 // 204800 B
  _Float16* xt = (_Float16*)((char*)d_ws + 204800);            // 5308416 B

  hipLaunchKernelGGL(wprep_kernel, dim3(400), dim3(256), 0, stream, W, wsh);
  hipLaunchKernelGGL(xprep_kernel, dim3(2592), dim3(256), 0, stream, inp, xt);
  hipLaunchKernelGGL(capsconv_mfma_kernel, dim3(2048), dim3(256), 0, stream,
                     xt, wsh, bv, out);
}

// Round 19
// 48.756 us; speedup vs baseline: 1.5741x; 1.5741x over previous
//
#include <hip/hip_runtime.h>

// ConvCapsuleLayer r19: r18 with cvt_pkrtz return-type fix (bit_cast to f16x2).
// r15 base (best, 49.5us) + fdot2 weighted-sum: votes kept in regs as fp16
// pairs over ii; route packed to fp16 pairs -> wsum = 16 fdot2 (was 32 fmaf).
// rt=0 uses route=0.125 uniform (exact fp16). Agreement/nsq stay f32 + DPP.

typedef __attribute__((ext_vector_type(2))) _Float16 f16x2;
typedef __attribute__((ext_vector_type(8))) _Float16 f16x8;
typedef __attribute__((ext_vector_type(16))) float f32x16;

union f16x8u { f16x8 v; f16x2 d[4]; unsigned short s[8]; unsigned int u32[4]; unsigned long long u[2]; };
union f16x2u { f16x2 v; unsigned int u; unsigned short s[2]; };

__device__ __forceinline__ unsigned short f2h(float x) {
  union { _Float16 h; unsigned short u; } v;
  v.h = (_Float16)x;
  return v.u;
}

__device__ __forceinline__ f16x2 pk2h(float a, float b) {
  return __builtin_bit_cast(f16x2, __builtin_amdgcn_cvt_pkrtz(a, b));
}

template<int CTRL>
__device__ __forceinline__ float dpp_mov(float x) {
  return __builtin_bit_cast(float, __builtin_amdgcn_update_dpp(
      0, __builtin_bit_cast(int, x), CTRL, 0xF, 0xF, true));
}
// sum over 8-lane c-group: ^1, ^2, ^7(mirror) — order-free for sums
__device__ __forceinline__ float sum8_dpp(float x) {
  x += dpp_mov<0xB1>(x);    // quad_perm [1,0,3,2]  : ^1
  x += dpp_mov<0x4E>(x);    // quad_perm [2,3,0,1]  : ^2
  x += dpp_mov<0x141>(x);   // row_half_mirror      : ^7
  return x;
}

// W[5][5][16][256] f32 -> wsh fp16 [khkw 25][ch 256][ia 16]
__global__ __launch_bounds__(256) void wprep_kernel(
    const float* __restrict__ W, unsigned short* __restrict__ wsh) {
  int t = blockIdx.x * 256 + threadIdx.x;      // 102400 total
  int khkw = t >> 12;
  int rem  = t & 4095;
  int ch = rem >> 4, ia = rem & 15;
  wsh[t] = f2h(W[khkw * 4096 + ia * 256 + ch]);
}

// LDS map (36864 B):
//   conv phase:  X fp16 [kh 5][ii 8, stride 400B][wl 12][ia 16] = 16000 B @0
//   transpose:   votesT fp16 [w 8, stride 4608][grp 64, stride 72][j 4][ii 8] @0
__global__ __launch_bounds__(256, 2) void capsconv_mfma_kernel(
    const float* __restrict__ inp,            // [16][32][32][8][16] f32
    const unsigned short* __restrict__ wsh,   // [25][256][16] fp16
    const float* __restrict__ bias,           // [256] f32
    float* __restrict__ out)                  // [16][32][32][256] f32
{
  __shared__ char smem[36864];
  const _Float16* wshh = (const _Float16*)wsh;

  const int tid  = threadIdx.x;
  const int wid  = tid >> 6;          // wave 0..3: conv ch quarter
  const int lane = tid & 63;
  const int sub  = lane >> 5;
  const int ln31 = lane & 31;

  const int bid = blockIdx.x;         // 2048 = ((bb*32 + h)*4 + wq)
  const int wq = bid & 3;
  const int h  = (bid >> 2) & 31;
  const int bb = bid >> 7;
  const int i_src  = bb >> 1;         // TF reshape scramble (verified r1/r4)
  const int b_base = (bb & 1) * 8;

  // ---------------- stage 5 X rows: [kh][ii][wl 12][ia], halo +-2 ----------------
  for (int e = tid; e < 1920; e += 256) {
    int kh = e / 384; int r1 = e - kh * 384;
    int ii = r1 / 48; int r2 = r1 - ii * 48;
    int wl = r2 >> 2; int iaq = r2 & 3;
    int hh = h + kh - 2;
    int wsrc = wq * 8 + wl - 2;
    float4 v = make_float4(0.f, 0.f, 0.f, 0.f);
    if ((unsigned)hh < 32u && (unsigned)wsrc < 32u)
      v = *(const float4*)(inp +
          ((((size_t)(b_base + ii) * 32 + hh) * 32 + wsrc) * 8 + i_src) * 16 + iaq * 4);
    union { _Float16 hx[4]; unsigned long long u; } pkk;
    pkk.hx[0] = (_Float16)v.x; pkk.hx[1] = (_Float16)v.y;
    pkk.hx[2] = (_Float16)v.z; pkk.hx[3] = (_Float16)v.w;
    *(unsigned long long*)(smem + kh * 3200 + ii * 400 + wl * 32 + iaq * 8) = pkk.u;
  }
  __syncthreads();

  // ---------------- conv: 25 taps, acc[2][2]; bfrag reused across mt ----------------
  f32x16 acc[2][2];
  #pragma unroll
  for (int mt = 0; mt < 2; ++mt)
    #pragma unroll
    for (int nt = 0; nt < 2; ++nt)
      #pragma unroll
      for (int e = 0; e < 16; ++e) acc[mt][nt][e] = 0.f;

  const char* aBase = smem + (ln31 & 7) * 400 + (ln31 >> 3) * 32 + sub * 16;
  const _Float16* bBase = wshh + (wid * 64 + ln31) * 16 + sub * 8;

  #pragma unroll
  for (int kh = 0; kh < 5; ++kh) {
    #pragma unroll
    for (int kw = 0; kw < 5; ++kw) {
      f16x8 af0 = *(const f16x8*)(aBase + kh * 3200 + kw * 32);          // rows mt=0
      f16x8 af1 = *(const f16x8*)(aBase + kh * 3200 + (kw + 4) * 32);    // rows mt=1
      f16x8 bf0 = *(const f16x8*)(bBase + (size_t)(kh * 5 + kw) * 4096);
      f16x8 bf1 = *(const f16x8*)(bBase + (size_t)(kh * 5 + kw) * 4096 + 512);
      acc[0][0] = __builtin_amdgcn_mfma_f32_32x32x16_f16(af0, bf0, acc[0][0], 0, 0, 0);
      acc[0][1] = __builtin_amdgcn_mfma_f32_32x32x16_f16(af0, bf1, acc[0][1], 0, 0, 0);
      acc[1][0] = __builtin_amdgcn_mfma_f32_32x32x16_f16(af1, bf0, acc[1][0], 0, 0, 0);
      acc[1][1] = __builtin_amdgcn_mfma_f32_32x32x16_f16(af1, bf1, acc[1][1], 0, 0, 0);
    }
  }

  // ---------------- votesT: direct b64 writes, no shuffles ----------------
  __syncthreads();   // X region dead; votesT aliases it
  #pragma unroll
  for (int mt = 0; mt < 2; ++mt)
    #pragma unroll
    for (int nt = 0; nt < 2; ++nt) {
      int ch = wid * 64 + nt * 32 + ln31;
      char* base = smem + (ch >> 2) * 72 + (ch & 3) * 16 + sub * 8;
      #pragma unroll
      for (int q = 0; q < 4; ++q) {
        f16x2u lo, hi;
        lo.v = f16x2{(_Float16)acc[mt][nt][q * 4 + 0], (_Float16)acc[mt][nt][q * 4 + 1]};
        hi.v = f16x2{(_Float16)acc[mt][nt][q * 4 + 2], (_Float16)acc[mt][nt][q * 4 + 3]};
        unsigned long long u = (unsigned long long)lo.u |
                               ((unsigned long long)hi.u << 32);
        *(unsigned long long*)(base + (mt * 4 + q) * 4608) = u;
      }
    }
  __syncthreads();

  // ---------------- routing: wave wid owns w = wid*2+p; fdot2 wsum + DPP ----------------
  const int k = lane & 7;             // c-group slot; c = lane>>3
  f16x8u vvh[2][4];                   // fp16 pairs over ii (fdot2 operand shape)
  float vv[2][4][8];                  // f32 copies for agreement/nsq
  #pragma unroll
  for (int p = 0; p < 2; ++p)
    #pragma unroll
    for (int j = 0; j < 4; ++j) {
      vvh[p][j].v = *(const f16x8*)(smem + (wid * 2 + p) * 4608 + lane * 72 + j * 16);
      #pragma unroll
      for (int ii = 0; ii < 8; ++ii) vv[p][j][ii] = (float)vvh[p][j].v[ii];
    }
  const float4 bv4 = *(const float4*)(bias + lane * 4);
  const float bvj[4] = {bv4.x, bv4.y, bv4.z, bv4.w};

  float logit_k[2] = {0.f, 0.f};
  float pre[2][4], scale[2] = {0.f, 0.f};

  #pragma unroll
  for (int rt = 0; rt < 3; ++rt) {
    #pragma unroll
    for (int p = 0; p < 2; ++p) {
      f16x2 rpk[4];                   // route pairs (ii 2k, 2k+1)
      if (rt == 0) {
        #pragma unroll
        for (int i = 0; i < 4; ++i)
          rpk[i] = f16x2{(_Float16)0.125f, (_Float16)0.125f};
      } else {
        // softmax over c: lanes stride 8 -> ^8 via DPP ror8, ^16/^32 via shfl
        float mx = logit_k[p];
        mx = fmaxf(mx, dpp_mov<0x128>(mx));             // row_ror:8 = ^8
        mx = fmaxf(mx, __shfl_xor(mx, 16, 64));
        mx = fmaxf(mx, __shfl_xor(mx, 32, 64));
        float e = __expf(logit_k[p] - mx);
        float den = e;
        den += dpp_mov<0x128>(den);
        den += __shfl_xor(den, 16, 64);
        den += __shfl_xor(den, 32, 64);
        float route_k = e / den;
        int cbase = lane & 56;          // c<<3
        #pragma unroll
        for (int i = 0; i < 4; ++i) {
          float r0 = __shfl(route_k, cbase | (2 * i), 64);
          float r1 = __shfl(route_k, cbase | (2 * i + 1), 64);
          rpk[i] = pk2h(r0, r1);
        }
      }
      // weighted sum: 4 fdot2 per channel j
      #pragma unroll
      for (int j = 0; j < 4; ++j) {
        float pp = bvj[j];
        #pragma unroll
        for (int d = 0; d < 4; ++d)
          pp = __builtin_amdgcn_fdot2(vvh[p][j].d[d], rpk[d], pp, false);
        pre[p][j] = pp;
      }
      // squash scale: nsq over 32 atoms = 8-lane c-group DPP reduce
      float nsq = pre[p][0] * pre[p][0] + pre[p][1] * pre[p][1] +
                  pre[p][2] * pre[p][2] + pre[p][3] * pre[p][3];
      nsq = sum8_dpp(nsq);
      scale[p] = sqrtf(nsq) / (1.f + nsq);
      if (rt < 2) {
        // agreement: dot8[ii] over 32 atoms via DPP trees (0 DS ops)
        float dot8[8];
        #pragma unroll
        for (int ii = 0; ii < 8; ++ii) {
          float d = vv[p][0][ii] * pre[p][0];
          d = fmaf(vv[p][1][ii], pre[p][1], d);
          d = fmaf(vv[p][2][ii], pre[p][2], d);
          d = fmaf(vv[p][3][ii], pre[p][3], d);
          dot8[ii] = sum8_dpp(d);
        }
        bool b0 = (k & 1), b1 = (k & 2), b2 = (k & 4);
        float e0 = b0 ? dot8[1] : dot8[0];
        float e1 = b0 ? dot8[3] : dot8[2];
        float e2 = b0 ? dot8[5] : dot8[4];
        float e3 = b0 ? dot8[7] : dot8[6];
        float f0 = b1 ? e1 : e0;
        float f1 = b1 ? e3 : e2;
        logit_k[p] = fmaf(scale[p], b2 ? f1 : f0, logit_k[p]);
      }
    }
  }
  // final act = pre * scale; coalesced float4 per position
  const size_t base8 = (size_t)((bb * 32 + h) * 32 + wq * 8);
  #pragma unroll
  for (int p = 0; p < 2; ++p) {
    float4 o = make_float4(pre[p][0] * scale[p], pre[p][1] * scale[p],
                           pre[p][2] * scale[p], pre[p][3] * scale[p]);
    *(float4*)(out + (base8 + wid * 2 + p) * 256 + lane * 4) = o;
  }
}

extern "C" void kernel_launch(void* const* d_in, const int* in_sizes, int n_in,
                              void* d_out, int out_size, void* d_ws, size_t ws_size,
                              hipStream_t stream) {
  (void)in_sizes; (void)n_in; (void)ws_size; (void)out_size;
  const float* inp  = (const float*)d_in[0];
  const float* W    = (const float*)d_in[1];
  const float* bv   = (const float*)d_in[2];
  float* out        = (float*)d_out;
  unsigned short* wsh = (unsigned short*)d_ws;   // 204800 B used

  hipLaunchKernelGGL(wprep_kernel, dim3(400), dim3(256), 0, stream, W, wsh);
  hipLaunchKernelGGL(capsconv_mfma_kernel, dim3(2048), dim3(256), 0, stream,
                     inp, wsh, bv, out);
}